// Round 7
// baseline (924.931 us; speedup 1.0000x reference)
//
#include <hip/hip_runtime.h>
#include <math.h>

// VecPointNet on MI355X, round 7: two-phase exact KNN (presample top-2 ->
// tau gate -> rank-count select), gbias folded into layerB, quad-buffered g,
// first-layer wout stores (no acc memset). GEMMs stay double-bf16 hi/lo MFMA.

#define EPSV 1e-12f
#define KCAP 96

typedef unsigned short us;
typedef unsigned long long u64;
typedef __attribute__((ext_vector_type(8))) short short8;
typedef __attribute__((ext_vector_type(4))) float f32x4;

__device__ __forceinline__ us f2bf(float f) {
    unsigned int u = __float_as_uint(f);
    unsigned int r = (u + 0x7FFFu + ((u >> 16) & 1u)) >> 16;
    return (us)r;
}
__device__ __forceinline__ float bf2f(us s) {
    return __uint_as_float(((unsigned int)s) << 16);
}
__device__ __forceinline__ void wsplit(float v, us* __restrict__ hi, us* __restrict__ lo,
                                       size_t o) {
    us h = f2bf(v);
    hi[o] = h;
    lo[o] = f2bf(v - bf2f(h));
}
// monotone (order-preserving incl. negatives) fp32 -> u32
__device__ __forceinline__ unsigned int fflip(float f) {
    unsigned int u = __float_as_uint(f);
    return (u & 0x80000000u) ? ~u : (u | 0x80000000u);
}

// ---------------------------------------------------------------- KNN
// 8 queries/block x 32 subs, 2048 blocks. Exact stable top-16:
//  A) per-sub top-2 of 64 candidates (cheap body)
//  B) tau = 16th-smallest of the 64 presample keys (>= true 16th always)
//  C) append all keys <= tau to per-query buffer (expected ~25, cap 96)
//  D) rank-count in buffer -> key with rank r<16 written at slot r.
// Keys = (fflip(d2)<<32)|idx are unique -> stable order matches np top_k.
__global__ __launch_bounds__(256) void knn_kernel(const float* __restrict__ x,
                                                  int* __restrict__ idx) {
    __shared__ float px[2048], py[2048], pz[2048], psq[2048];
    __shared__ u64 pre[8][64];
    __shared__ u64 buf[8][KCAP];
    __shared__ u64 tauv[8];
    __shared__ int cnt[8];
    int t = threadIdx.x;
    int b = blockIdx.y, q0 = blockIdx.x * 8;
    for (int i = t; i < 2048; i += 256) {
        float vx = x[b * 6144 + i], vy = x[b * 6144 + 2048 + i], vz = x[b * 6144 + 4096 + i];
        px[i] = vx; py[i] = vy; pz[i] = vz;
        psq[i] = __fadd_rn(__fadd_rn(__fmul_rn(vx, vx), __fmul_rn(vy, vy)), __fmul_rn(vz, vz));
    }
    if (t < 8) cnt[t] = 0;
    __syncthreads();
    int lq = t >> 5, sub = t & 31;
    int q = q0 + lq;
    float qx = px[q], qy = py[q], qz = pz[q];
    float sqn = psq[q];

    // Phase A: per-sub top-2 (k0 <= k1)
    u64 k0 = ~0ull, k1 = ~0ull;
    unsigned f1 = 0xffffffffu;
    for (int jj = 0; jj < 64; ++jj) {
        int m = sub + jj * 32;
        float dot = __fadd_rn(__fadd_rn(__fmul_rn(qx, px[m]), __fmul_rn(qy, py[m])),
                              __fmul_rn(qz, pz[m]));
        float d2 = __fsub_rn(__fadd_rn(sqn, psq[m]), __fmul_rn(2.0f, dot));
        unsigned ff = fflip(d2);
        if (ff < f1) {  // ties lose (later idx => larger key) - matches stable top_k
            u64 key = (((u64)ff) << 32) | (unsigned)m;
            bool lt0 = key < k0;
            k1 = lt0 ? k0 : key;
            k0 = lt0 ? key : k0;
            f1 = (unsigned)(k1 >> 32);
        }
    }
    pre[lq][2 * sub] = k0;
    pre[lq][2 * sub + 1] = k1;
    __syncthreads();

    // Phase B: tau = key with rank 15 among the 64 presample keys
    {
        int ra = 0, rb = 0;
        for (int j = 0; j < 64; ++j) {
            u64 pj = pre[lq][j];
            ra += (pj < k0);
            rb += (pj < k1);
        }
        if (ra == 15) tauv[lq] = k0;
        if (rb == 15) tauv[lq] = k1;
    }
    __syncthreads();
    u64 tau = tauv[lq];
    unsigned tauhi = (unsigned)(tau >> 32);

    // Phase C: gated append
    for (int jj = 0; jj < 64; ++jj) {
        int m = sub + jj * 32;
        float dot = __fadd_rn(__fadd_rn(__fmul_rn(qx, px[m]), __fmul_rn(qy, py[m])),
                              __fmul_rn(qz, pz[m]));
        float d2 = __fsub_rn(__fadd_rn(sqn, psq[m]), __fmul_rn(2.0f, dot));
        unsigned ff = fflip(d2);
        if (ff <= tauhi) {
            u64 key = (((u64)ff) << 32) | (unsigned)m;
            if (key <= tau) {
                int pos = atomicAdd(&cnt[lq], 1);
                if (pos < KCAP) buf[lq][pos] = key;
            }
        }
    }
    __syncthreads();

    // Phase D: rank-count -> output slot = global rank
    int c = min(cnt[lq], KCAP);
    for (int s = sub; s < c; s += 32) {
        u64 k = buf[lq][s];
        int r = 0;
        for (int j = 0; j < c; ++j) r += (buf[lq][j] < k);
        if (r < 16) idx[(b * 2048 + q) * 16 + r] = (int)(unsigned)(k & 0xffffffffull);
    }
}

// ---------------------------------------------------------------- precompute
__global__ __launch_bounds__(256) void precompute_kernel(
    const float* __restrict__ Win, const float* __restrict__ Wdin,
    const float* __restrict__ Ws, const float* __restrict__ Wds,
    const float* __restrict__ Gs, const float* __restrict__ Gds,
    const float* __restrict__ Wout,
    us* __restrict__ W1h, us* __restrict__ W1l,
    us* __restrict__ W2h, us* __restrict__ W2l,
    float* __restrict__ Wg, us* __restrict__ Woh, us* __restrict__ Wol,
    float* __restrict__ Mbuf, float* __restrict__ Gbuf) {
    __shared__ float row[128];
    int blk = blockIdx.x, t = threadIdx.x;
    if (blk < 512) {
        int l = blk >> 7, i = blk & 127;
        if (t < 128) row[t] = Wds[l * 16384 + i * 128 + t];
        __syncthreads();
        if (t < 128) {
            float acc = 0.f;
            for (int m = 0; m < 128; ++m) acc += row[m] * Ws[l * 16384 + m * 128 + t];
            wsplit(acc, W1h, W1l, (size_t)l * 32768 + (128 + i) * 128 + t);
            wsplit(Ws[l * 16384 + i * 128 + t], W1h, W1l, (size_t)l * 32768 + i * 128 + t);
        }
    } else if (blk < 1024) {
        int l = (blk - 512) >> 7, i = (blk - 512) & 127;
        if (t < 128) row[t] = Gds[l * 16384 + i * 128 + t];
        __syncthreads();
        float acc = 0.f;
        for (int m = 0; m < 128; ++m) acc += row[m] * Gs[l * 32768 + m * 256 + t];
        if (t < 128) {
            wsplit(acc, W2h, W2l, (size_t)l * 32768 + (128 + i) * 128 + t);
            wsplit(Gs[l * 32768 + i * 256 + t], W2h, W2l, (size_t)l * 32768 + i * 128 + t);
        } else {
            Wg[l * 32768 + (128 + i) * 128 + (t - 128)] = acc;
            Wg[l * 32768 + i * 128 + (t - 128)] = Gs[l * 32768 + i * 256 + t];
        }
    } else if (blk == 1024) {
        if (t < 128) {
            float a0 = 0.f, a1 = 0.f, a2 = 0.f;
            for (int m = 0; m < 128; ++m) {
                float w = Wdin[t * 128 + m];
                a0 += w * Win[m * 3];
                a1 += w * Win[m * 3 + 1];
                a2 += w * Win[m * 3 + 2];
            }
            Mbuf[t * 3] = a0; Mbuf[t * 3 + 1] = a1; Mbuf[t * 3 + 2] = a2;
        } else if (t < 137) {
            int qq = t - 128, a = qq / 3, bb = qq - 3 * a;
            float acc = 0.f;
            for (int m = 0; m < 128; ++m) acc += Win[m * 3 + a] * Win[m * 3 + bb];
            Gbuf[qq] = acc;
        }
    } else {  // Wout slices, blk = 1025+l
        int l = blk - 1025;
        for (int i = t; i < 16384; i += 256) {
            int r = i >> 7, j = i & 127;
            wsplit(Wout[r * 512 + l * 128 + j], Woh, Wol, (size_t)l * 16384 + r * 128 + j);
        }
    }
}

// ---------------------------------------------------------------- stage 1
__global__ __launch_bounds__(256) void stage1_kernel(
    const float* __restrict__ x, const int* __restrict__ idx,
    const float* __restrict__ Win, const float* __restrict__ Mbuf,
    const float* __restrict__ Gbuf, us* __restrict__ hhi, us* __restrict__ hlo) {
    __shared__ float Yb[2][16][10];
    __shared__ float Pb[2][16][6];
    int t = threadIdx.x;
    int blk = blockIdx.x;
    int b = blk >> 10, n0 = (blk & 1023) * 2;
    if (t < 32) {
        int pt = t >> 4, k = t & 15;
        int n = n0 + pt, gpt = b * 2048 + n;
        float pxv = x[b * 6144 + n], pyv = x[b * 6144 + 2048 + n], pzv = x[b * 6144 + 4096 + n];
        float pn = sqrtf(pxv * pxv + pyv * pyv + pzv * pzv);
        float inv = 1.f / fmaxf(pn, EPSV);
        float dx = pxv * inv, dy = pyv * inv, dz = pzv * inv;
        int m = idx[gpt * 16 + k];
        float qx = x[b * 6144 + m], qy = x[b * 6144 + 2048 + m], qz = x[b * 6144 + 4096 + m];
        float Y[9];
        Y[0] = dy * qz - dz * qy; Y[1] = dz * qx - dx * qz; Y[2] = dx * qy - dy * qx;
        Y[3] = qx - pxv; Y[4] = qy - pyv; Y[5] = qz - pzv;
        Y[6] = pxv; Y[7] = pyv; Y[8] = pzv;
        float P[6];
        P[0] = Y[0] * Y[0] + Y[1] * Y[1] + Y[2] * Y[2];
        P[1] = Y[0] * Y[3] + Y[1] * Y[4] + Y[2] * Y[5];
        P[2] = Y[0] * Y[6] + Y[1] * Y[7] + Y[2] * Y[8];
        P[3] = Y[3] * Y[3] + Y[4] * Y[4] + Y[5] * Y[5];
        P[4] = Y[3] * Y[6] + Y[4] * Y[7] + Y[5] * Y[8];
        P[5] = Y[6] * Y[6] + Y[7] * Y[7] + Y[8] * Y[8];
        float nv2 = Gbuf[0] * P[0] + Gbuf[4] * P[3] + Gbuf[8] * P[5] +
                    (Gbuf[1] + Gbuf[3]) * P[1] + (Gbuf[2] + Gbuf[6]) * P[2] +
                    (Gbuf[5] + Gbuf[7]) * P[4];
        float s = 1.f / fmaxf(sqrtf(nv2), EPSV);
#pragma unroll
        for (int j = 0; j < 9; ++j) Yb[pt][k][j] = Y[j];
        Yb[pt][k][9] = s;
#pragma unroll
        for (int j = 0; j < 6; ++j) Pb[pt][k][j] = P[j];
    }
    __syncthreads();
    int pt = t >> 7, h = t & 127;
    int n = n0 + pt;
    float w0 = Win[h * 3], w1 = Win[h * 3 + 1], w2 = Win[h * 3 + 2];
    float m0 = Mbuf[h * 3], m1 = Mbuf[h * 3 + 1], m2 = Mbuf[h * 3 + 2];
    float cA0 = w0 * m0, cA3 = w1 * m1, cA5 = w2 * m2;
    float cA1 = w0 * m1 + w1 * m0, cA2 = w0 * m2 + w2 * m0, cA4 = w1 * m2 + w2 * m1;
    float cR0 = m0 * m0, cR3 = m1 * m1, cR5 = m2 * m2;
    float cR1 = 2.f * m0 * m1, cR2 = 2.f * m0 * m2, cR4 = 2.f * m1 * m2;
    float base[3] = {0.f, 0.f, 0.f}, corr[3] = {0.f, 0.f, 0.f};
    for (int k = 0; k < 16; ++k) {
        const float* Y = Yb[pt][k];
        const float* P = Pb[pt][k];
        float s = Y[9];
        float a = cA0 * P[0] + cA1 * P[1] + cA2 * P[2] + cA3 * P[3] + cA4 * P[4] + cA5 * P[5];
        float r2 = cR0 * P[0] + cR1 * P[1] + cR2 * P[2] + cR3 * P[3] + cR4 * P[4] + cR5 * P[5];
        float r = sqrtf(fmaxf(r2, 0.f));
        float D = fmaxf(s * r, EPSV);
        float dot = s * s * a / D;
        float wc = fmaxf(-dot, 0.f) * s / D;
#pragma unroll
        for (int c = 0; c < 3; ++c) {
            float yb = w0 * Y[c] + w1 * Y[3 + c] + w2 * Y[6 + c];
            float ym = m0 * Y[c] + m1 * Y[3 + c] + m2 * Y[6 + c];
            base[c] += s * yb;
            corr[c] += wc * ym;
        }
    }
#pragma unroll
    for (int c = 0; c < 3; ++c)
        wsplit((base[c] + corr[c]) * (1.f / 16.f), hhi, hlo,
               (size_t)(b * 2048 + n) * 384 + c * 128 + h);
}

#define MFMA_BF16 __builtin_amdgcn_mfma_f32_16x16x32_bf16

// ---------------------------------------------------------------- layer A (hi/lo MFMA)
__global__ __launch_bounds__(512, 4) void layerA_kernel(
    const us* __restrict__ Xhi, const us* __restrict__ Xlo,
    const us* __restrict__ Whi, const us* __restrict__ Wlo,
    us* __restrict__ Hhi, us* __restrict__ Hlo, float* __restrict__ g) {
    __shared__ float ebuf[2 * 128 * 49];
    __shared__ float spt[16];
    int t = threadIdx.x;
    int blk = blockIdx.x;
    int b = blk >> 7, n0 = (blk & 127) * 16;
    size_t pbase = (size_t)(b * 2048 + n0);
    const us* xh = Xhi + pbase * 384;
    const us* xl = Xlo + pbase * 384;
    int lane = t & 63, wv = t >> 6;
    int r15 = lane & 15, quad = lane >> 4;
    int arow = 32 * wv + r15;

    f32x4 acc[2][3];
#pragma unroll
    for (int i = 0; i < 2; ++i)
#pragma unroll
        for (int j = 0; j < 3; ++j) acc[i][j] = (f32x4){0.f, 0.f, 0.f, 0.f};

#pragma unroll 2
    for (int kc4 = 0; kc4 < 4; ++kc4) {
        int ko = kc4 * 32 + quad * 8;
        short8 a0h = *(const short8*)(Whi + arow * 128 + ko);
        short8 a1h = *(const short8*)(Whi + (arow + 16) * 128 + ko);
        short8 a0l = *(const short8*)(Wlo + arow * 128 + ko);
        short8 a1l = *(const short8*)(Wlo + (arow + 16) * 128 + ko);
        short8 b0h = *(const short8*)(xh + r15 * 128 + ko);
        short8 b1h = *(const short8*)(xh + (r15 + 16) * 128 + ko);
        short8 b2h = *(const short8*)(xh + (r15 + 32) * 128 + ko);
        short8 b0l = *(const short8*)(xl + r15 * 128 + ko);
        short8 b1l = *(const short8*)(xl + (r15 + 16) * 128 + ko);
        short8 b2l = *(const short8*)(xl + (r15 + 32) * 128 + ko);
        acc[0][0] = MFMA_BF16(a0h, b0h, acc[0][0], 0, 0, 0);
        acc[0][1] = MFMA_BF16(a0h, b1h, acc[0][1], 0, 0, 0);
        acc[0][2] = MFMA_BF16(a0h, b2h, acc[0][2], 0, 0, 0);
        acc[1][0] = MFMA_BF16(a1h, b0h, acc[1][0], 0, 0, 0);
        acc[1][1] = MFMA_BF16(a1h, b1h, acc[1][1], 0, 0, 0);
        acc[1][2] = MFMA_BF16(a1h, b2h, acc[1][2], 0, 0, 0);
        acc[0][0] = MFMA_BF16(a0h, b0l, acc[0][0], 0, 0, 0);
        acc[0][1] = MFMA_BF16(a0h, b1l, acc[0][1], 0, 0, 0);
        acc[0][2] = MFMA_BF16(a0h, b2l, acc[0][2], 0, 0, 0);
        acc[1][0] = MFMA_BF16(a1h, b0l, acc[1][0], 0, 0, 0);
        acc[1][1] = MFMA_BF16(a1h, b1l, acc[1][1], 0, 0, 0);
        acc[1][2] = MFMA_BF16(a1h, b2l, acc[1][2], 0, 0, 0);
        acc[0][0] = MFMA_BF16(a0l, b0h, acc[0][0], 0, 0, 0);
        acc[0][1] = MFMA_BF16(a0l, b1h, acc[0][1], 0, 0, 0);
        acc[0][2] = MFMA_BF16(a0l, b2h, acc[0][2], 0, 0, 0);
        acc[1][0] = MFMA_BF16(a1l, b0h, acc[1][0], 0, 0, 0);
        acc[1][1] = MFMA_BF16(a1l, b1h, acc[1][1], 0, 0, 0);
        acc[1][2] = MFMA_BF16(a1l, b2h, acc[1][2], 0, 0, 0);
    }

    float* kbuf = ebuf;
    float* vbuf = ebuf + 128 * 49;
#pragma unroll
    for (int ti = 0; ti < 2; ++ti) {
        int grow0 = (2 * wv + ti) * 16 + quad * 4;
#pragma unroll
        for (int nt = 0; nt < 3; ++nt) {
            int col = nt * 16 + r15;
#pragma unroll
            for (int r = 0; r < 4; ++r) {
                int grow = grow0 + r;
                float val = acc[ti][nt][r];
                if (wv < 4) vbuf[grow * 49 + col] = val;
                else kbuf[(grow - 128) * 49 + col] = val;
            }
        }
    }
    __syncthreads();

    {
        int p = t >> 5, sub = t & 31;
        float S = 0.f;
#pragma unroll
        for (int j = 0; j < 12; ++j) {
            int e = sub * 12 + j;
            int c = e >> 7, row = e & 127;
            float v = vbuf[row * 49 + 3 * p + c];
            S += v * v;
        }
#pragma unroll
        for (int off = 16; off; off >>= 1) S += __shfl_down(S, off, 32);
        if (sub == 0) spt[p] = 1.f / fmaxf(sqrtf(S), EPSV);
    }
    __syncthreads();

    {
        int row = t & 127, pg = t >> 7;
        float gsum[3] = {0.f, 0.f, 0.f};
#pragma unroll
        for (int pi = 0; pi < 4; ++pi) {
            int p = pg * 4 + pi;
            float s = spt[p];
            float vx = vbuf[row * 49 + 3 * p + 0];
            float vy = vbuf[row * 49 + 3 * p + 1];
            float vz = vbuf[row * 49 + 3 * p + 2];
            float kx = kbuf[row * 49 + 3 * p + 0];
            float ky = kbuf[row * 49 + 3 * p + 1];
            float kz = kbuf[row * 49 + 3 * p + 2];
            float kn = sqrtf(kx * kx + ky * ky + kz * kz);
            float D = fmaxf(s * kn, EPSV);
            float dot = s * s * (vx * kx + vy * ky + vz * kz) / D;
            float f = fmaxf(-dot, 0.f) * s / D;
            float o0 = s * vx + f * kx;
            float o1 = s * vy + f * ky;
            float o2 = s * vz + f * kz;
            size_t gp = (pbase + p) * 384;
            wsplit(o0, Hhi, Hlo, gp + row);
            wsplit(o1, Hhi, Hlo, gp + 128 + row);
            wsplit(o2, Hhi, Hlo, gp + 256 + row);
            gsum[0] += o0; gsum[1] += o1; gsum[2] += o2;
        }
#pragma unroll
        for (int c = 0; c < 3; ++c)
            atomicAdd(&g[b * 384 + c * 128 + row], gsum[c]);
    }
}

// ---------------------------------------------------------------- layer B + Wout (fused)
// Bias computed in-kernel from g (replaces gbias dispatch). FIRST=1: wout
// stores into acc (layer 0) instead of RMW.
template <int FIRST>
__global__ __launch_bounds__(512, 4) void layerB_wout_kernel(
    const us* __restrict__ Xhi, const us* __restrict__ Xlo,
    const us* __restrict__ Whi, const us* __restrict__ Wlo,
    const float* __restrict__ g, const float* __restrict__ Wgl,
    const us* __restrict__ Woh, const us* __restrict__ Wol,
    us* __restrict__ Hhi, us* __restrict__ Hlo,
    float* __restrict__ accb) {
    __shared__ float ebuf[2 * 128 * 49];
    __shared__ float biasl[768];
    __shared__ float spt[16];
    int t = threadIdx.x;
    int blk = blockIdx.x;
    int b = blk >> 7, n0 = (blk & 127) * 16;
    size_t pbase = (size_t)(b * 2048 + n0);
    const us* xh = Xhi + pbase * 384;
    const us* xl = Xlo + pbase * 384;
    int lane = t & 63, wv = t >> 6;
    int r15 = lane & 15, quad = lane >> 4;
    int arow = 32 * wv + r15;

    // bias[c*256+r] = (Wg[r] . g[b][c]) / 2048  (visible after the post-K-loop barrier)
    for (int i = t; i < 768; i += 512) {
        int r = i & 255, c = i >> 8;
        const float* wr = Wgl + r * 128;
        const float* gv = g + b * 384 + c * 128;
        float a = 0.f;
        for (int j = 0; j < 128; j += 4) {
            float4 w4 = *(const float4*)(wr + j);
            float4 g4 = *(const float4*)(gv + j);
            a += w4.x * g4.x + w4.y * g4.y + w4.z * g4.z + w4.w * g4.w;
        }
        biasl[i] = a * (1.f / 2048.f);
    }

    f32x4 acc[2][3];
#pragma unroll
    for (int i = 0; i < 2; ++i)
#pragma unroll
        for (int j = 0; j < 3; ++j) acc[i][j] = (f32x4){0.f, 0.f, 0.f, 0.f};

#pragma unroll 2
    for (int kc4 = 0; kc4 < 4; ++kc4) {
        int ko = kc4 * 32 + quad * 8;
        short8 a0h = *(const short8*)(Whi + arow * 128 + ko);
        short8 a1h = *(const short8*)(Whi + (arow + 16) * 128 + ko);
        short8 a0l = *(const short8*)(Wlo + arow * 128 + ko);
        short8 a1l = *(const short8*)(Wlo + (arow + 16) * 128 + ko);
        short8 b0h = *(const short8*)(xh + r15 * 128 + ko);
        short8 b1h = *(const short8*)(xh + (r15 + 16) * 128 + ko);
        short8 b2h = *(const short8*)(xh + (r15 + 32) * 128 + ko);
        short8 b0l = *(const short8*)(xl + r15 * 128 + ko);
        short8 b1l = *(const short8*)(xl + (r15 + 16) * 128 + ko);
        short8 b2l = *(const short8*)(xl + (r15 + 32) * 128 + ko);
        acc[0][0] = MFMA_BF16(a0h, b0h, acc[0][0], 0, 0, 0);
        acc[0][1] = MFMA_BF16(a0h, b1h, acc[0][1], 0, 0, 0);
        acc[0][2] = MFMA_BF16(a0h, b2h, acc[0][2], 0, 0, 0);
        acc[1][0] = MFMA_BF16(a1h, b0h, acc[1][0], 0, 0, 0);
        acc[1][1] = MFMA_BF16(a1h, b1h, acc[1][1], 0, 0, 0);
        acc[1][2] = MFMA_BF16(a1h, b2h, acc[1][2], 0, 0, 0);
        acc[0][0] = MFMA_BF16(a0h, b0l, acc[0][0], 0, 0, 0);
        acc[0][1] = MFMA_BF16(a0h, b1l, acc[0][1], 0, 0, 0);
        acc[0][2] = MFMA_BF16(a0h, b2l, acc[0][2], 0, 0, 0);
        acc[1][0] = MFMA_BF16(a1h, b0l, acc[1][0], 0, 0, 0);
        acc[1][1] = MFMA_BF16(a1h, b1l, acc[1][1], 0, 0, 0);
        acc[1][2] = MFMA_BF16(a1h, b2l, acc[1][2], 0, 0, 0);
        acc[0][0] = MFMA_BF16(a0l, b0h, acc[0][0], 0, 0, 0);
        acc[0][1] = MFMA_BF16(a0l, b1h, acc[0][1], 0, 0, 0);
        acc[0][2] = MFMA_BF16(a0l, b2h, acc[0][2], 0, 0, 0);
        acc[1][0] = MFMA_BF16(a1l, b0h, acc[1][0], 0, 0, 0);
        acc[1][1] = MFMA_BF16(a1l, b1h, acc[1][1], 0, 0, 0);
        acc[1][2] = MFMA_BF16(a1l, b2h, acc[1][2], 0, 0, 0);
    }

    float* kbuf = ebuf;
    float* vbuf = ebuf + 128 * 49;
#pragma unroll
    for (int ti = 0; ti < 2; ++ti) {
        int grow0 = (2 * wv + ti) * 16 + quad * 4;
#pragma unroll
        for (int nt = 0; nt < 3; ++nt) {
            int col = nt * 16 + r15;
#pragma unroll
            for (int r = 0; r < 4; ++r) {
                int grow = grow0 + r;
                float val = acc[ti][nt][r];
                if (wv < 4) vbuf[grow * 49 + col] = val;
                else kbuf[(grow - 128) * 49 + col] = val;
            }
        }
    }
    __syncthreads();

    {
        int p = t >> 5, sub = t & 31;
        float S = 0.f;
#pragma unroll
        for (int j = 0; j < 12; ++j) {
            int e = sub * 12 + j;
            int c = e >> 7, row = e & 127;
            float v = vbuf[row * 49 + 3 * p + c] + biasl[c * 256 + row];
            S += v * v;
        }
#pragma unroll
        for (int off = 16; off; off >>= 1) S += __shfl_down(S, off, 32);
        if (sub == 0) spt[p] = 1.f / fmaxf(sqrtf(S), EPSV);
    }
    __syncthreads();

    int row = t & 127, pg = t >> 7;
    us ohi[4][3], olo[4][3];
    {
        float bv[3], bk[3];
#pragma unroll
        for (int c = 0; c < 3; ++c) {
            bv[c] = biasl[c * 256 + row];
            bk[c] = biasl[c * 256 + 128 + row];
        }
#pragma unroll
        for (int pi = 0; pi < 4; ++pi) {
            int p = pg * 4 + pi;
            float s = spt[p];
            float vx = vbuf[row * 49 + 3 * p + 0] + bv[0];
            float vy = vbuf[row * 49 + 3 * p + 1] + bv[1];
            float vz = vbuf[row * 49 + 3 * p + 2] + bv[2];
            float kx = kbuf[row * 49 + 3 * p + 0] + bk[0];
            float ky = kbuf[row * 49 + 3 * p + 1] + bk[1];
            float kz = kbuf[row * 49 + 3 * p + 2] + bk[2];
            float kn = sqrtf(kx * kx + ky * ky + kz * kz);
            float D = fmaxf(s * kn, EPSV);
            float dot = s * s * (vx * kx + vy * ky + vz * kz) / D;
            float f = fmaxf(-dot, 0.f) * s / D;
            float o[3];
            o[0] = s * vx + f * kx;
            o[1] = s * vy + f * ky;
            o[2] = s * vz + f * kz;
            size_t gp = (pbase + p) * 384;
#pragma unroll
            for (int c = 0; c < 3; ++c) {
                us h = f2bf(o[c]);
                us l = f2bf(o[c] - bf2f(h));
                ohi[pi][c] = h; olo[pi][c] = l;
                Hhi[gp + c * 128 + row] = h;
                Hlo[gp + c * 128 + row] = l;
            }
        }
    }
    __syncthreads();  // kbuf/vbuf reads done -> reuse ebuf for fragments

    us* xfh = (us*)ebuf;          // [col][swizzled k], 48*128
    us* xfl = xfh + 6144;
    {
        int chunk = row >> 3, off = row & 7;
#pragma unroll
        for (int pi = 0; pi < 4; ++pi) {
            int p = pg * 4 + pi;
#pragma unroll
            for (int c = 0; c < 3; ++c) {
                int col = p * 3 + c;
                int sw = (chunk ^ (col & 15)) * 8 + off;
                xfh[col * 128 + sw] = ohi[pi][c];
                xfl[col * 128 + sw] = olo[pi][c];
            }
        }
    }
    __syncthreads();

    f32x4 wacc[3];
#pragma unroll
    for (int j = 0; j < 3; ++j) wacc[j] = (f32x4){0.f, 0.f, 0.f, 0.f};
    int warow = wv * 16 + r15;
#pragma unroll 2
    for (int kc4 = 0; kc4 < 4; ++kc4) {
        int ko = kc4 * 32 + quad * 8;
        short8 ah = *(const short8*)(Woh + warow * 128 + ko);
        short8 al = *(const short8*)(Wol + warow * 128 + ko);
        int cb = kc4 * 4 + quad;
        short8 bh[3], bl[3];
#pragma unroll
        for (int nt = 0; nt < 3; ++nt) {
            int col = nt * 16 + r15;
            int sw = (cb ^ (col & 15)) * 8;
            bh[nt] = *(const short8*)(xfh + col * 128 + sw);
            bl[nt] = *(const short8*)(xfl + col * 128 + sw);
        }
#pragma unroll
        for (int nt = 0; nt < 3; ++nt) {
            wacc[nt] = MFMA_BF16(ah, bh[nt], wacc[nt], 0, 0, 0);
            wacc[nt] = MFMA_BF16(ah, bl[nt], wacc[nt], 0, 0, 0);
            wacc[nt] = MFMA_BF16(al, bh[nt], wacc[nt], 0, 0, 0);
        }
    }
#pragma unroll
    for (int nt = 0; nt < 3; ++nt) {
        int col = nt * 16 + r15;
        int p = col / 3, c = col - 3 * p;
        size_t gp = (pbase + p) * 384 + c * 128 + wv * 16 + quad * 4;
        if (FIRST) {
            *(float4*)&accb[gp] = make_float4(wacc[nt][0], wacc[nt][1], wacc[nt][2], wacc[nt][3]);
        } else {
            float4 old = *(const float4*)&accb[gp];
            old.x += wacc[nt][0]; old.y += wacc[nt][1];
            old.z += wacc[nt][2]; old.w += wacc[nt][3];
            *(float4*)&accb[gp] = old;
        }
    }
}

// ---------------------------------------------------------------- transpose + mean
__global__ __launch_bounds__(256) void out_kernel(const float* __restrict__ acc,
                                                  float* __restrict__ out1,
                                                  float* __restrict__ out0) {
    __shared__ float tile[64][33];
    int b = blockIdx.z, n0 = blockIdx.x * 64, j0 = blockIdx.y * 32;
    int t = threadIdx.x;
#pragma unroll
    for (int r = 0; r < 8; ++r) {
        int nf = (t >> 5) + r * 8, jf = t & 31;
        tile[nf][jf] = acc[(size_t)(b * 2048 + n0 + nf) * 384 + j0 + jf];
    }
    __syncthreads();
#pragma unroll
    for (int r = 0; r < 8; ++r) {
        int jf = (t >> 6) + r * 4, nf = t & 63;
        int j = j0 + jf;
        int ridx = (j & 127) * 3 + (j >> 7);
        out1[((size_t)b * 384 + ridx) * 2048 + n0 + nf] = tile[nf][jf];
    }
    if (t < 32) {
        float s = 0.f;
#pragma unroll
        for (int n = 0; n < 64; ++n) s += tile[n][t];
        int j = j0 + t;
        int ridx = (j & 127) * 3 + (j >> 7);
        atomicAdd(&out0[b * 384 + ridx], s * (1.f / 2048.f));
    }
}

// ---------------------------------------------------------------- launch
extern "C" void kernel_launch(void* const* d_in, const int* in_sizes, int n_in,
                              void* d_out, int out_size, void* d_ws, size_t ws_size,
                              hipStream_t stream) {
    const float* x    = (const float*)d_in[0];
    const float* Win  = (const float*)d_in[1];
    const float* Wdin = (const float*)d_in[2];
    const float* Ws   = (const float*)d_in[3];
    const float* Wds  = (const float*)d_in[4];
    const float* Gs   = (const float*)d_in[5];
    const float* Gds  = (const float*)d_in[6];
    const float* Wout = (const float*)d_in[7];

    float* out0 = (float*)d_out;   // (B,CD,3) = 3072
    float* out1 = out0 + 3072;     // (B,CD,3,N)

    char* ws = (char*)d_ws;
    int* idx = (int*)ws;                            // 1 MB
    us* hAhi = (us*)(ws + (1 << 20));               // 6291456 bf16 each
    us* hAlo = hAhi + 6291456;
    us* hBhi = hAlo + 6291456;
    us* hBlo = hBhi + 6291456;
    float* acc = (float*)(hBlo + 6291456);          // 6291456 f32
    float* g4 = acc + 6291456;                      // 4 x 3072 (per-layer g)
    us* W1h = (us*)(g4 + 12288);                    // 131072 each
    us* W1l = W1h + 131072;
    us* W2h = W1l + 131072;
    us* W2l = W2h + 131072;
    us* Woh = W2l + 131072;                         // 65536 each
    us* Wol = Woh + 65536;
    float* Wg = (float*)(Wol + 65536);              // 131072 f32
    float* Mbuf = Wg + 131072;                      // 384
    float* Gbuf = Mbuf + 384;                       // 16

    hipMemsetAsync(out0, 0, (size_t)3072 * 4, stream);
    hipMemsetAsync(g4, 0, (size_t)12288 * 4, stream);

    knn_kernel<<<dim3(256, 8), 256, 0, stream>>>(x, idx);
    precompute_kernel<<<1029, 256, 0, stream>>>(Win, Wdin, Ws, Wds, Gs, Gds, Wout,
                                                W1h, W1l, W2h, W2l, Wg, Woh, Wol,
                                                Mbuf, Gbuf);
    stage1_kernel<<<8192, 256, 0, stream>>>(x, idx, Win, Mbuf, Gbuf, hAhi, hAlo);
    for (int l = 0; l < 4; ++l) {
        layerA_kernel<<<1024, 512, 0, stream>>>(hAhi, hAlo, W1h + l * 32768,
                                                W1l + l * 32768, hBhi, hBlo,
                                                g4 + l * 3072);
        if (l == 0)
            layerB_wout_kernel<1><<<1024, 512, 0, stream>>>(
                hBhi, hBlo, W2h + l * 32768, W2l + l * 32768, g4 + l * 3072,
                Wg + l * 32768, Woh + l * 16384, Wol + l * 16384, hAhi, hAlo, acc);
        else
            layerB_wout_kernel<0><<<1024, 512, 0, stream>>>(
                hBhi, hBlo, W2h + l * 32768, W2l + l * 32768, g4 + l * 3072,
                Wg + l * 32768, Woh + l * 16384, Wol + l * 16384, hAhi, hAlo, acc);
    }
    out_kernel<<<dim3(32, 12, 8), 256, 0, stream>>>(acc, out1, out0);
}

// Round 8
// 712.408 us; speedup vs baseline: 1.2983x; 1.2983x over previous
//
#include <hip/hip_runtime.h>
#include <math.h>

// VecPointNet on MI355X, round 8: in-register layer epilogue via B-col remap
// (point = lane&15, comp = nt) -> VN activation lane-local, no 50KB LDS v/k
// exchange; padded bf16 stash for coalesced H dump + wout B-fragments; bias
// reverted to tiny gbias kernel (R7's per-block fold cost ~30us/dispatch).

#define EPSV 1e-12f
#define KCAP 96

typedef unsigned short us;
typedef unsigned long long u64;
typedef __attribute__((ext_vector_type(8))) short short8;
typedef __attribute__((ext_vector_type(4))) float f32x4;

__device__ __forceinline__ us f2bf(float f) {
    unsigned int u = __float_as_uint(f);
    unsigned int r = (u + 0x7FFFu + ((u >> 16) & 1u)) >> 16;
    return (us)r;
}
__device__ __forceinline__ float bf2f(us s) {
    return __uint_as_float(((unsigned int)s) << 16);
}
__device__ __forceinline__ void wsplit(float v, us* __restrict__ hi, us* __restrict__ lo,
                                       size_t o) {
    us h = f2bf(v);
    hi[o] = h;
    lo[o] = f2bf(v - bf2f(h));
}
__device__ __forceinline__ unsigned int fflip(float f) {
    unsigned int u = __float_as_uint(f);
    return (u & 0x80000000u) ? ~u : (u | 0x80000000u);
}

#define MFMA_BF16 __builtin_amdgcn_mfma_f32_16x16x32_bf16
__device__ __forceinline__ void mfma3(f32x4& acc, short8 ah, short8 al, short8 bh, short8 bl) {
    acc = MFMA_BF16(ah, bh, acc, 0, 0, 0);
    acc = MFMA_BF16(ah, bl, acc, 0, 0, 0);
    acc = MFMA_BF16(al, bh, acc, 0, 0, 0);
}

// ---------------------------------------------------------------- KNN (unchanged R7)
__global__ __launch_bounds__(256) void knn_kernel(const float* __restrict__ x,
                                                  int* __restrict__ idx) {
    __shared__ float px[2048], py[2048], pz[2048], psq[2048];
    __shared__ u64 pre[8][64];
    __shared__ u64 buf[8][KCAP];
    __shared__ u64 tauv[8];
    __shared__ int cnt[8];
    int t = threadIdx.x;
    int b = blockIdx.y, q0 = blockIdx.x * 8;
    for (int i = t; i < 2048; i += 256) {
        float vx = x[b * 6144 + i], vy = x[b * 6144 + 2048 + i], vz = x[b * 6144 + 4096 + i];
        px[i] = vx; py[i] = vy; pz[i] = vz;
        psq[i] = __fadd_rn(__fadd_rn(__fmul_rn(vx, vx), __fmul_rn(vy, vy)), __fmul_rn(vz, vz));
    }
    if (t < 8) cnt[t] = 0;
    __syncthreads();
    int lq = t >> 5, sub = t & 31;
    int q = q0 + lq;
    float qx = px[q], qy = py[q], qz = pz[q];
    float sqn = psq[q];

    u64 k0 = ~0ull, k1 = ~0ull;
    unsigned f1 = 0xffffffffu;
    for (int jj = 0; jj < 64; ++jj) {
        int m = sub + jj * 32;
        float dot = __fadd_rn(__fadd_rn(__fmul_rn(qx, px[m]), __fmul_rn(qy, py[m])),
                              __fmul_rn(qz, pz[m]));
        float d2 = __fsub_rn(__fadd_rn(sqn, psq[m]), __fmul_rn(2.0f, dot));
        unsigned ff = fflip(d2);
        if (ff < f1) {
            u64 key = (((u64)ff) << 32) | (unsigned)m;
            bool lt0 = key < k0;
            k1 = lt0 ? k0 : key;
            k0 = lt0 ? key : k0;
            f1 = (unsigned)(k1 >> 32);
        }
    }
    pre[lq][2 * sub] = k0;
    pre[lq][2 * sub + 1] = k1;
    __syncthreads();
    {
        int ra = 0, rb = 0;
        for (int j = 0; j < 64; ++j) {
            u64 pj = pre[lq][j];
            ra += (pj < k0);
            rb += (pj < k1);
        }
        if (ra == 15) tauv[lq] = k0;
        if (rb == 15) tauv[lq] = k1;
    }
    __syncthreads();
    u64 tau = tauv[lq];
    unsigned tauhi = (unsigned)(tau >> 32);
    for (int jj = 0; jj < 64; ++jj) {
        int m = sub + jj * 32;
        float dot = __fadd_rn(__fadd_rn(__fmul_rn(qx, px[m]), __fmul_rn(qy, py[m])),
                              __fmul_rn(qz, pz[m]));
        float d2 = __fsub_rn(__fadd_rn(sqn, psq[m]), __fmul_rn(2.0f, dot));
        unsigned ff = fflip(d2);
        if (ff <= tauhi) {
            u64 key = (((u64)ff) << 32) | (unsigned)m;
            if (key <= tau) {
                int pos = atomicAdd(&cnt[lq], 1);
                if (pos < KCAP) buf[lq][pos] = key;
            }
        }
    }
    __syncthreads();
    int c = min(cnt[lq], KCAP);
    for (int s = sub; s < c; s += 32) {
        u64 k = buf[lq][s];
        int r = 0;
        for (int j = 0; j < c; ++j) r += (buf[lq][j] < k);
        if (r < 16) idx[(b * 2048 + q) * 16 + r] = (int)(unsigned)(k & 0xffffffffull);
    }
}

// ---------------------------------------------------------------- precompute (unchanged)
__global__ __launch_bounds__(256) void precompute_kernel(
    const float* __restrict__ Win, const float* __restrict__ Wdin,
    const float* __restrict__ Ws, const float* __restrict__ Wds,
    const float* __restrict__ Gs, const float* __restrict__ Gds,
    const float* __restrict__ Wout,
    us* __restrict__ W1h, us* __restrict__ W1l,
    us* __restrict__ W2h, us* __restrict__ W2l,
    float* __restrict__ Wg, us* __restrict__ Woh, us* __restrict__ Wol,
    float* __restrict__ Mbuf, float* __restrict__ Gbuf) {
    __shared__ float row[128];
    int blk = blockIdx.x, t = threadIdx.x;
    if (blk < 512) {
        int l = blk >> 7, i = blk & 127;
        if (t < 128) row[t] = Wds[l * 16384 + i * 128 + t];
        __syncthreads();
        if (t < 128) {
            float acc = 0.f;
            for (int m = 0; m < 128; ++m) acc += row[m] * Ws[l * 16384 + m * 128 + t];
            wsplit(acc, W1h, W1l, (size_t)l * 32768 + (128 + i) * 128 + t);
            wsplit(Ws[l * 16384 + i * 128 + t], W1h, W1l, (size_t)l * 32768 + i * 128 + t);
        }
    } else if (blk < 1024) {
        int l = (blk - 512) >> 7, i = (blk - 512) & 127;
        if (t < 128) row[t] = Gds[l * 16384 + i * 128 + t];
        __syncthreads();
        float acc = 0.f;
        for (int m = 0; m < 128; ++m) acc += row[m] * Gs[l * 32768 + m * 256 + t];
        if (t < 128) {
            wsplit(acc, W2h, W2l, (size_t)l * 32768 + (128 + i) * 128 + t);
            wsplit(Gs[l * 32768 + i * 256 + t], W2h, W2l, (size_t)l * 32768 + i * 128 + t);
        } else {
            Wg[l * 32768 + (128 + i) * 128 + (t - 128)] = acc;
            Wg[l * 32768 + i * 128 + (t - 128)] = Gs[l * 32768 + i * 256 + t];
        }
    } else if (blk == 1024) {
        if (t < 128) {
            float a0 = 0.f, a1 = 0.f, a2 = 0.f;
            for (int m = 0; m < 128; ++m) {
                float w = Wdin[t * 128 + m];
                a0 += w * Win[m * 3];
                a1 += w * Win[m * 3 + 1];
                a2 += w * Win[m * 3 + 2];
            }
            Mbuf[t * 3] = a0; Mbuf[t * 3 + 1] = a1; Mbuf[t * 3 + 2] = a2;
        } else if (t < 137) {
            int qq = t - 128, a = qq / 3, bb = qq - 3 * a;
            float acc = 0.f;
            for (int m = 0; m < 128; ++m) acc += Win[m * 3 + a] * Win[m * 3 + bb];
            Gbuf[qq] = acc;
        }
    } else {
        int l = blk - 1025;
        for (int i = t; i < 16384; i += 256) {
            int r = i >> 7, j = i & 127;
            wsplit(Wout[r * 512 + l * 128 + j], Woh, Wol, (size_t)l * 16384 + r * 128 + j);
        }
    }
}

// ---------------------------------------------------------------- stage 1 (unchanged)
__global__ __launch_bounds__(256) void stage1_kernel(
    const float* __restrict__ x, const int* __restrict__ idx,
    const float* __restrict__ Win, const float* __restrict__ Mbuf,
    const float* __restrict__ Gbuf, us* __restrict__ hhi, us* __restrict__ hlo) {
    __shared__ float Yb[2][16][10];
    __shared__ float Pb[2][16][6];
    int t = threadIdx.x;
    int blk = blockIdx.x;
    int b = blk >> 10, n0 = (blk & 1023) * 2;
    if (t < 32) {
        int pt = t >> 4, k = t & 15;
        int n = n0 + pt, gpt = b * 2048 + n;
        float pxv = x[b * 6144 + n], pyv = x[b * 6144 + 2048 + n], pzv = x[b * 6144 + 4096 + n];
        float pn = sqrtf(pxv * pxv + pyv * pyv + pzv * pzv);
        float inv = 1.f / fmaxf(pn, EPSV);
        float dx = pxv * inv, dy = pyv * inv, dz = pzv * inv;
        int m = idx[gpt * 16 + k];
        float qx = x[b * 6144 + m], qy = x[b * 6144 + 2048 + m], qz = x[b * 6144 + 4096 + m];
        float Y[9];
        Y[0] = dy * qz - dz * qy; Y[1] = dz * qx - dx * qz; Y[2] = dx * qy - dy * qx;
        Y[3] = qx - pxv; Y[4] = qy - pyv; Y[5] = qz - pzv;
        Y[6] = pxv; Y[7] = pyv; Y[8] = pzv;
        float P[6];
        P[0] = Y[0] * Y[0] + Y[1] * Y[1] + Y[2] * Y[2];
        P[1] = Y[0] * Y[3] + Y[1] * Y[4] + Y[2] * Y[5];
        P[2] = Y[0] * Y[6] + Y[1] * Y[7] + Y[2] * Y[8];
        P[3] = Y[3] * Y[3] + Y[4] * Y[4] + Y[5] * Y[5];
        P[4] = Y[3] * Y[6] + Y[4] * Y[7] + Y[5] * Y[8];
        P[5] = Y[6] * Y[6] + Y[7] * Y[7] + Y[8] * Y[8];
        float nv2 = Gbuf[0] * P[0] + Gbuf[4] * P[3] + Gbuf[8] * P[5] +
                    (Gbuf[1] + Gbuf[3]) * P[1] + (Gbuf[2] + Gbuf[6]) * P[2] +
                    (Gbuf[5] + Gbuf[7]) * P[4];
        float s = 1.f / fmaxf(sqrtf(nv2), EPSV);
#pragma unroll
        for (int j = 0; j < 9; ++j) Yb[pt][k][j] = Y[j];
        Yb[pt][k][9] = s;
#pragma unroll
        for (int j = 0; j < 6; ++j) Pb[pt][k][j] = P[j];
    }
    __syncthreads();
    int pt = t >> 7, h = t & 127;
    int n = n0 + pt;
    float w0 = Win[h * 3], w1 = Win[h * 3 + 1], w2 = Win[h * 3 + 2];
    float m0 = Mbuf[h * 3], m1 = Mbuf[h * 3 + 1], m2 = Mbuf[h * 3 + 2];
    float cA0 = w0 * m0, cA3 = w1 * m1, cA5 = w2 * m2;
    float cA1 = w0 * m1 + w1 * m0, cA2 = w0 * m2 + w2 * m0, cA4 = w1 * m2 + w2 * m1;
    float cR0 = m0 * m0, cR3 = m1 * m1, cR5 = m2 * m2;
    float cR1 = 2.f * m0 * m1, cR2 = 2.f * m0 * m2, cR4 = 2.f * m1 * m2;
    float base[3] = {0.f, 0.f, 0.f}, corr[3] = {0.f, 0.f, 0.f};
    for (int k = 0; k < 16; ++k) {
        const float* Y = Yb[pt][k];
        const float* P = Pb[pt][k];
        float s = Y[9];
        float a = cA0 * P[0] + cA1 * P[1] + cA2 * P[2] + cA3 * P[3] + cA4 * P[4] + cA5 * P[5];
        float r2 = cR0 * P[0] + cR1 * P[1] + cR2 * P[2] + cR3 * P[3] + cR4 * P[4] + cR5 * P[5];
        float r = sqrtf(fmaxf(r2, 0.f));
        float D = fmaxf(s * r, EPSV);
        float dot = s * s * a / D;
        float wc = fmaxf(-dot, 0.f) * s / D;
#pragma unroll
        for (int c = 0; c < 3; ++c) {
            float yb = w0 * Y[c] + w1 * Y[3 + c] + w2 * Y[6 + c];
            float ym = m0 * Y[c] + m1 * Y[3 + c] + m2 * Y[6 + c];
            base[c] += s * yb;
            corr[c] += wc * ym;
        }
    }
#pragma unroll
    for (int c = 0; c < 3; ++c)
        wsplit((base[c] + corr[c]) * (1.f / 16.f), hhi, hlo,
               (size_t)(b * 2048 + n) * 384 + c * 128 + h);
}

// ---------------------------------------------------------------- layer A (v2)
// 512 thr / 8 waves, 16 pts. B col map: point = lane&15, comp = nt. Wave wv
// owns v-rows [16wv,+16) and k-rows [128+16wv,+16) -> activation lane-local.
__global__ __launch_bounds__(512, 6) void layerA_kernel(
    const us* __restrict__ Xhi, const us* __restrict__ Xlo,
    const us* __restrict__ Whi, const us* __restrict__ Wlo,
    us* __restrict__ Hhi, us* __restrict__ Hlo, float* __restrict__ g) {
    __shared__ __align__(16) us stash[2 * 6272];   // hi | lo, [p][c*128+k], p-stride 392
    __shared__ float colsum[8][16];
    __shared__ float spt[16];
    us* sh = stash;
    us* sl = stash + 6272;
    int t = threadIdx.x;
    int blk = blockIdx.x;
    int b = blk >> 7, n0 = (blk & 127) * 16;
    size_t pbase = (size_t)(b * 2048 + n0);
    int lane = t & 63, wv = t >> 6;
    int r15 = lane & 15, quad = lane >> 4;
    const us* xh = Xhi + (pbase + r15) * 384;
    const us* xl = Xlo + (pbase + r15) * 384;
    const us* wvh = Whi + (16 * wv + r15) * 128;
    const us* wvl = Wlo + (16 * wv + r15) * 128;
    const us* wkh = Whi + (128 + 16 * wv + r15) * 128;
    const us* wkl = Wlo + (128 + 16 * wv + r15) * 128;

    f32x4 av[3], ak[3];
#pragma unroll
    for (int j = 0; j < 3; ++j) { av[j] = (f32x4){0.f, 0.f, 0.f, 0.f}; ak[j] = av[j]; }

#pragma unroll
    for (int kc4 = 0; kc4 < 4; ++kc4) {
        int ko = kc4 * 32 + quad * 8;
        short8 avh = *(const short8*)(wvh + ko);
        short8 avl = *(const short8*)(wvl + ko);
        short8 akh = *(const short8*)(wkh + ko);
        short8 akl = *(const short8*)(wkl + ko);
        short8 bh0 = *(const short8*)(xh + ko);
        short8 bh1 = *(const short8*)(xh + 128 + ko);
        short8 bh2 = *(const short8*)(xh + 256 + ko);
        short8 bl0 = *(const short8*)(xl + ko);
        short8 bl1 = *(const short8*)(xl + 128 + ko);
        short8 bl2 = *(const short8*)(xl + 256 + ko);
        mfma3(av[0], avh, avl, bh0, bl0);
        mfma3(av[1], avh, avl, bh1, bl1);
        mfma3(av[2], avh, avl, bh2, bl2);
        mfma3(ak[0], akh, akl, bh0, bl0);
        mfma3(ak[1], akh, akl, bh1, bl1);
        mfma3(ak[2], akh, akl, bh2, bl2);
    }

    // per-point ||v||^2: lane partial (12 terms) -> quad reduce -> LDS combine
    float S = 0.f;
#pragma unroll
    for (int nt = 0; nt < 3; ++nt)
#pragma unroll
        for (int reg = 0; reg < 4; ++reg) S += av[nt][reg] * av[nt][reg];
    S += __shfl_xor(S, 16, 64);
    S += __shfl_xor(S, 32, 64);
    if (quad == 0) colsum[wv][r15] = S;
    __syncthreads();
    if (t < 16) {
        float s = 0.f;
#pragma unroll
        for (int w = 0; w < 8; ++w) s += colsum[w][t];
        spt[t] = 1.f / fmaxf(sqrtf(s), EPSV);
    }
    __syncthreads();
    float s = spt[r15];
    int rowb = 16 * wv + quad * 4;
#pragma unroll
    for (int reg = 0; reg < 4; ++reg) {
        int row = rowb + reg;
        float vx = av[0][reg], vy = av[1][reg], vz = av[2][reg];
        float kx = ak[0][reg], ky = ak[1][reg], kz = ak[2][reg];
        float kn = sqrtf(kx * kx + ky * ky + kz * kz);
        float D = fmaxf(s * kn, EPSV);
        float dot = s * s * (vx * kx + vy * ky + vz * kz) / D;
        float f = fmaxf(-dot, 0.f) * s / D;
        float o0 = s * vx + f * kx;
        float o1 = s * vy + f * ky;
        float o2 = s * vz + f * kz;
        int sb = r15 * 392 + row;
        us h0 = f2bf(o0); sh[sb] = h0;           sl[sb] = f2bf(o0 - bf2f(h0));
        us h1 = f2bf(o1); sh[sb + 128] = h1;     sl[sb + 128] = f2bf(o1 - bf2f(h1));
        us h2 = f2bf(o2); sh[sb + 256] = h2;     sl[sb + 256] = f2bf(o2 - bf2f(h2));
        // g: reduce over the 16 points (lane bits 0..3)
        float g0 = o0, g1 = o1, g2 = o2;
#pragma unroll
        for (int m = 1; m < 16; m <<= 1) {
            g0 += __shfl_xor(g0, m, 64);
            g1 += __shfl_xor(g1, m, 64);
            g2 += __shfl_xor(g2, m, 64);
        }
        if (r15 == 0) {
            atomicAdd(&g[b * 384 + row], g0);
            atomicAdd(&g[b * 384 + 128 + row], g1);
            atomicAdd(&g[b * 384 + 256 + row], g2);
        }
    }
    __syncthreads();
    // coalesced 16B dump of H hi/lo
    for (int i = t; i < 768; i += 512) {
        int p = i / 48, rem = i - p * 48;
        int c = rem >> 4, k0 = (rem & 15) << 3;
        int lo_ = p * 392 + c * 128 + k0;
        size_t go = (pbase + p) * 384 + c * 128 + k0;
        *(uint4*)(Hhi + go) = *(const uint4*)(sh + lo_);
        *(uint4*)(Hlo + go) = *(const uint4*)(sl + lo_);
    }
}

// ---------------------------------------------------------------- gbias (restored)
__global__ __launch_bounds__(256) void gbias_kernel(const float* __restrict__ g,
                                                    const float* __restrict__ Wgl,
                                                    float* __restrict__ biasbuf) {
    __shared__ float gl[384];
    int b = blockIdx.x, r = threadIdx.x;
    for (int i = r; i < 384; i += 256) gl[i] = g[b * 384 + i] * (1.f / 2048.f);
    __syncthreads();
    float accv[3] = {0.f, 0.f, 0.f};
    const float4* wr = (const float4*)&Wgl[r * 128];
    for (int j = 0; j < 32; ++j) {
        float4 w4 = wr[j];
#pragma unroll
        for (int c = 0; c < 3; ++c) {
            float4 g4 = *(const float4*)&gl[c * 128 + 4 * j];
            accv[c] += w4.x * g4.x + w4.y * g4.y + w4.z * g4.z + w4.w * g4.w;
        }
    }
#pragma unroll
    for (int c = 0; c < 3; ++c) biasbuf[b * 768 + c * 256 + r] = accv[c];
}

// ---------------------------------------------------------------- layer B + Wout (v2)
template <int FIRST>
__global__ __launch_bounds__(512, 6) void layerB_wout_kernel(
    const us* __restrict__ Xhi, const us* __restrict__ Xlo,
    const us* __restrict__ Whi, const us* __restrict__ Wlo,
    const float* __restrict__ biasbuf,
    const us* __restrict__ Woh, const us* __restrict__ Wol,
    us* __restrict__ Hhi, us* __restrict__ Hlo, float* __restrict__ accb) {
    __shared__ __align__(16) us stash[2 * 6272];
    __shared__ float biasl[768];
    __shared__ float colsum[8][16];
    __shared__ float spt[16];
    us* sh = stash;
    us* sl = stash + 6272;
    int t = threadIdx.x;
    int blk = blockIdx.x;
    int b = blk >> 7, n0 = (blk & 127) * 16;
    size_t pbase = (size_t)(b * 2048 + n0);
    int lane = t & 63, wv = t >> 6;
    int r15 = lane & 15, quad = lane >> 4;
    const us* xh = Xhi + (pbase + r15) * 384;
    const us* xl = Xlo + (pbase + r15) * 384;
    const us* wvh = Whi + (16 * wv + r15) * 128;
    const us* wvl = Wlo + (16 * wv + r15) * 128;
    const us* wkh = Whi + (128 + 16 * wv + r15) * 128;
    const us* wkl = Wlo + (128 + 16 * wv + r15) * 128;

    for (int i = t; i < 768; i += 512) biasl[i] = biasbuf[b * 768 + i];

    f32x4 av[3], ak[3];
#pragma unroll
    for (int j = 0; j < 3; ++j) { av[j] = (f32x4){0.f, 0.f, 0.f, 0.f}; ak[j] = av[j]; }

#pragma unroll
    for (int kc4 = 0; kc4 < 4; ++kc4) {
        int ko = kc4 * 32 + quad * 8;
        short8 avh = *(const short8*)(wvh + ko);
        short8 avl = *(const short8*)(wvl + ko);
        short8 akh = *(const short8*)(wkh + ko);
        short8 akl = *(const short8*)(wkl + ko);
        short8 bh0 = *(const short8*)(xh + ko);
        short8 bh1 = *(const short8*)(xh + 128 + ko);
        short8 bh2 = *(const short8*)(xh + 256 + ko);
        short8 bl0 = *(const short8*)(xl + ko);
        short8 bl1 = *(const short8*)(xl + 128 + ko);
        short8 bl2 = *(const short8*)(xl + 256 + ko);
        mfma3(av[0], avh, avl, bh0, bl0);
        mfma3(av[1], avh, avl, bh1, bl1);
        mfma3(av[2], avh, avl, bh2, bl2);
        mfma3(ak[0], akh, akl, bh0, bl0);
        mfma3(ak[1], akh, akl, bh1, bl1);
        mfma3(ak[2], akh, akl, bh2, bl2);
    }
    __syncthreads();   // biasl visible

    int rowb = 16 * wv + quad * 4;
    float S = 0.f;
#pragma unroll
    for (int reg = 0; reg < 4; ++reg) {
        int row = rowb + reg;
#pragma unroll
        for (int c = 0; c < 3; ++c) {
            float v = av[c][reg] + biasl[c * 256 + row];
            S += v * v;
        }
    }
    S += __shfl_xor(S, 16, 64);
    S += __shfl_xor(S, 32, 64);
    if (quad == 0) colsum[wv][r15] = S;
    __syncthreads();
    if (t < 16) {
        float s = 0.f;
#pragma unroll
        for (int w = 0; w < 8; ++w) s += colsum[w][t];
        spt[t] = 1.f / fmaxf(sqrtf(s), EPSV);
    }
    __syncthreads();
    float s = spt[r15];
#pragma unroll
    for (int reg = 0; reg < 4; ++reg) {
        int row = rowb + reg;
        float vx = av[0][reg] + biasl[row];
        float vy = av[1][reg] + biasl[256 + row];
        float vz = av[2][reg] + biasl[512 + row];
        float kx = ak[0][reg] + biasl[128 + row];
        float ky = ak[1][reg] + biasl[384 + row];
        float kz = ak[2][reg] + biasl[640 + row];
        float kn = sqrtf(kx * kx + ky * ky + kz * kz);
        float D = fmaxf(s * kn, EPSV);
        float dot = s * s * (vx * kx + vy * ky + vz * kz) / D;
        float f = fmaxf(-dot, 0.f) * s / D;
        float o0 = s * vx + f * kx;
        float o1 = s * vy + f * ky;
        float o2 = s * vz + f * kz;
        int sb = r15 * 392 + row;
        us h0 = f2bf(o0); sh[sb] = h0;           sl[sb] = f2bf(o0 - bf2f(h0));
        us h1 = f2bf(o1); sh[sb + 128] = h1;     sl[sb + 128] = f2bf(o1 - bf2f(h1));
        us h2 = f2bf(o2); sh[sb + 256] = h2;     sl[sb + 256] = f2bf(o2 - bf2f(h2));
    }
    __syncthreads();
    // coalesced H dump
    for (int i = t; i < 768; i += 512) {
        int p = i / 48, rem = i - p * 48;
        int c = rem >> 4, k0 = (rem & 15) << 3;
        int lo_ = p * 392 + c * 128 + k0;
        size_t go = (pbase + p) * 384 + c * 128 + k0;
        *(uint4*)(Hhi + go) = *(const uint4*)(sh + lo_);
        *(uint4*)(Hlo + go) = *(const uint4*)(sl + lo_);
    }
    // wout GEMM: A rows 16wv..+16 from global, B from stash
    f32x4 wa[3];
#pragma unroll
    for (int j = 0; j < 3; ++j) wa[j] = (f32x4){0.f, 0.f, 0.f, 0.f};
    const us* woh = Woh + (16 * wv + r15) * 128;
    const us* wol = Wol + (16 * wv + r15) * 128;
#pragma unroll
    for (int kc4 = 0; kc4 < 4; ++kc4) {
        int ko = kc4 * 32 + quad * 8;
        short8 ah = *(const short8*)(woh + ko);
        short8 al = *(const short8*)(wol + ko);
#pragma unroll
        for (int nt = 0; nt < 3; ++nt) {
            short8 bh = *(const short8*)(sh + r15 * 392 + nt * 128 + ko);
            short8 bl = *(const short8*)(sl + r15 * 392 + nt * 128 + ko);
            mfma3(wa[nt], ah, al, bh, bl);
        }
    }
    __syncthreads();   // all stash reads (dump + fragments) done
    float* accf = (float*)stash;   // [p][c*128+k], p-stride 388
#pragma unroll
    for (int nt = 0; nt < 3; ++nt)
#pragma unroll
        for (int reg = 0; reg < 4; ++reg)
            accf[r15 * 388 + nt * 128 + rowb + reg] = wa[nt][reg];
    __syncthreads();
    for (int i = t; i < 1536; i += 512) {
        int p = i / 96, rem = i - p * 96;
        int c = rem >> 5, k4 = (rem & 31) << 2;
        float4 vv = *(const float4*)&accf[p * 388 + c * 128 + k4];
        size_t go = (pbase + p) * 384 + c * 128 + k4;
        if (FIRST) {
            *(float4*)&accb[go] = vv;
        } else {
            float4 old = *(const float4*)&accb[go];
            old.x += vv.x; old.y += vv.y; old.z += vv.z; old.w += vv.w;
            *(float4*)&accb[go] = old;
        }
    }
}

// ---------------------------------------------------------------- transpose + mean
__global__ __launch_bounds__(256) void out_kernel(const float* __restrict__ acc,
                                                  float* __restrict__ out1,
                                                  float* __restrict__ out0) {
    __shared__ float tile[64][33];
    int b = blockIdx.z, n0 = blockIdx.x * 64, j0 = blockIdx.y * 32;
    int t = threadIdx.x;
#pragma unroll
    for (int r = 0; r < 8; ++r) {
        int nf = (t >> 5) + r * 8, jf = t & 31;
        tile[nf][jf] = acc[(size_t)(b * 2048 + n0 + nf) * 384 + j0 + jf];
    }
    __syncthreads();
#pragma unroll
    for (int r = 0; r < 8; ++r) {
        int jf = (t >> 6) + r * 4, nf = t & 63;
        int j = j0 + jf;
        int ridx = (j & 127) * 3 + (j >> 7);
        out1[((size_t)b * 384 + ridx) * 2048 + n0 + nf] = tile[nf][jf];
    }
    if (t < 32) {
        float s = 0.f;
#pragma unroll
        for (int n = 0; n < 64; ++n) s += tile[n][t];
        int j = j0 + t;
        int ridx = (j & 127) * 3 + (j >> 7);
        atomicAdd(&out0[b * 384 + ridx], s * (1.f / 2048.f));
    }
}

// ---------------------------------------------------------------- launch
extern "C" void kernel_launch(void* const* d_in, const int* in_sizes, int n_in,
                              void* d_out, int out_size, void* d_ws, size_t ws_size,
                              hipStream_t stream) {
    const float* x    = (const float*)d_in[0];
    const float* Win  = (const float*)d_in[1];
    const float* Wdin = (const float*)d_in[2];
    const float* Ws   = (const float*)d_in[3];
    const float* Wds  = (const float*)d_in[4];
    const float* Gs   = (const float*)d_in[5];
    const float* Gds  = (const float*)d_in[6];
    const float* Wout = (const float*)d_in[7];

    float* out0 = (float*)d_out;   // (B,CD,3) = 3072
    float* out1 = out0 + 3072;     // (B,CD,3,N)

    char* ws = (char*)d_ws;
    int* idx = (int*)ws;                            // 1 MB
    us* hAhi = (us*)(ws + (1 << 20));               // 6291456 bf16 each
    us* hAlo = hAhi + 6291456;
    us* hBhi = hAlo + 6291456;
    us* hBlo = hBhi + 6291456;
    float* acc = (float*)(hBlo + 6291456);          // 6291456 f32
    float* g4 = acc + 6291456;                      // 4 x 3072
    us* W1h = (us*)(g4 + 12288);                    // 131072 each
    us* W1l = W1h + 131072;
    us* W2h = W1l + 131072;
    us* W2l = W2h + 131072;
    us* Woh = W2l + 131072;                         // 65536 each
    us* Wol = Woh + 65536;
    float* Wg = (float*)(Wol + 65536);              // 131072 f32
    float* Mbuf = Wg + 131072;                      // 384
    float* Gbuf = Mbuf + 384;                       // 16
    float* biasbuf = Gbuf + 16;                     // 6144

    hipMemsetAsync(out0, 0, (size_t)3072 * 4, stream);
    hipMemsetAsync(g4, 0, (size_t)12288 * 4, stream);

    knn_kernel<<<dim3(256, 8), 256, 0, stream>>>(x, idx);
    precompute_kernel<<<1029, 256, 0, stream>>>(Win, Wdin, Ws, Wds, Gs, Gds, Wout,
                                                W1h, W1l, W2h, W2l, Wg, Woh, Wol,
                                                Mbuf, Gbuf);
    stage1_kernel<<<8192, 256, 0, stream>>>(x, idx, Win, Mbuf, Gbuf, hAhi, hAlo);
    for (int l = 0; l < 4; ++l) {
        layerA_kernel<<<1024, 512, 0, stream>>>(hAhi, hAlo, W1h + l * 32768,
                                                W1l + l * 32768, hBhi, hBlo,
                                                g4 + l * 3072);
        gbias_kernel<<<8, 256, 0, stream>>>(g4 + l * 3072, Wg + l * 32768, biasbuf);
        if (l == 0)
            layerB_wout_kernel<1><<<1024, 512, 0, stream>>>(
                hBhi, hBlo, W2h + l * 32768, W2l + l * 32768, biasbuf,
                Woh + l * 16384, Wol + l * 16384, hAhi, hAlo, acc);
        else
            layerB_wout_kernel<0><<<1024, 512, 0, stream>>>(
                hBhi, hBlo, W2h + l * 32768, W2l + l * 32768, biasbuf,
                Woh + l * 16384, Wol + l * 16384, hAhi, hAlo, acc);
    }
    out_kernel<<<dim3(32, 12, 8), 256, 0, stream>>>(acc, out1, out0);
}